// Round 4
// baseline (1802.053 us; speedup 1.0000x reference)
//
#include <hip/hip_runtime.h>
#include <math.h>

#define N_NODES 10000
#define N_EDGES 100000
#define N_GRAPH 64
#define CDIM 128
#define HCDIM 256
#define C3DIM 384

typedef unsigned short u16;
typedef __attribute__((ext_vector_type(8))) short bf16x8;
typedef __attribute__((ext_vector_type(4))) float f32x4;

__device__ __forceinline__ u16 f2bf(float f) {
  union { float f; unsigned int u; } x; x.f = f;
  unsigned int u = x.u + 0x7fffu + ((x.u >> 16) & 1u);
  return (u16)(u >> 16);
}
__device__ __forceinline__ float bf2f(u16 h) {
  union { unsigned int u; float f; } x; x.u = ((unsigned int)h) << 16;
  return x.f;
}

// ---------------- generic fp32 GEMM (small/odd-K cases) ----------------------
template<int ACT>
__global__ __launch_bounds__(256) void gemm_kernel(
    const float* __restrict__ A, const float* __restrict__ W,
    const float* __restrict__ bias, float* __restrict__ Y,
    int M, int K, int N) {
  __shared__ float As[16][68];
  __shared__ float Bs[16][65];
  const int tid = threadIdx.x;
  const int bm = blockIdx.y * 64, bn = blockIdx.x * 64;
  const int tx = tid & 15, ty = tid >> 4;
  float acc[4][4] = {};
  for (int k0 = 0; k0 < K; k0 += 16) {
#pragma unroll
    for (int i = 0; i < 4; ++i) {
      int l = tid + i * 256;
      int kk = l & 15, m = l >> 4;
      int gm = bm + m, gk = k0 + kk;
      As[kk][m] = (gm < M && gk < K) ? A[(size_t)gm * K + gk] : 0.f;
    }
#pragma unroll
    for (int i = 0; i < 4; ++i) {
      int l = tid + i * 256;
      int n = l & 63, kk = l >> 6;
      int gk = k0 + kk, gn = bn + n;
      Bs[kk][n] = (gk < K && gn < N) ? W[(size_t)gk * N + gn] : 0.f;
    }
    __syncthreads();
#pragma unroll
    for (int kk = 0; kk < 16; ++kk) {
      float a[4], b[4];
#pragma unroll
      for (int i = 0; i < 4; ++i) a[i] = As[kk][ty * 4 + i];
#pragma unroll
      for (int j = 0; j < 4; ++j) b[j] = Bs[kk][tx * 4 + j];
#pragma unroll
      for (int i = 0; i < 4; ++i)
#pragma unroll
        for (int j = 0; j < 4; ++j) acc[i][j] += a[i] * b[j];
    }
    __syncthreads();
  }
#pragma unroll
  for (int i = 0; i < 4; ++i) {
    int gm = bm + ty * 4 + i;
    if (gm >= M) continue;
#pragma unroll
    for (int j = 0; j < 4; ++j) {
      int gn = bn + tx * 4 + j;
      if (gn >= N) continue;
      float val = acc[i][j] + (bias ? bias[gn] : 0.f);
      if (ACT == 1) val = val / (1.f + expf(-val));
      Y[(size_t)gm * N + gn] = val;
    }
  }
}

// ---------------- MFMA dense GEMM: Y[M,N] = Ab[M,K] @ WT[N,K]^T (+bias) ------
// Ab bf16 row-major, WT bf16 [N][K] (W transposed). K % 32 == 0, N % 64 == 0.
// Block: 4 waves; tile 128 rows x 64 cols; wave w: rows w*32..w*32+31.
template<int OUT_BF16>
__global__ __launch_bounds__(256) void mfma_gemm_kernel(
    const u16* __restrict__ Ab, const u16* __restrict__ WT,
    const float* __restrict__ bias, void* __restrict__ Y,
    int M, int K, int N) {
  const int tid = threadIdx.x;
  const int w = tid >> 6, l = tid & 63;
  const int lq = l >> 4, ln = l & 15;
  const int bm = blockIdx.y * 128, bn = blockIdx.x * 64;
  int ra = bm + w * 32 + ln;      if (ra > M - 1) ra = M - 1;
  int rb = bm + w * 32 + 16 + ln; if (rb > M - 1) rb = M - 1;
  f32x4 acc[2][4];
#pragma unroll
  for (int g = 0; g < 2; ++g)
#pragma unroll
    for (int nt = 0; nt < 4; ++nt) acc[g][nt] = {0.f, 0.f, 0.f, 0.f};
  for (int k0 = 0; k0 < K; k0 += 32) {
    bf16x8 a0 = *(const bf16x8*)&Ab[(size_t)ra * K + k0 + lq * 8];
    bf16x8 a1 = *(const bf16x8*)&Ab[(size_t)rb * K + k0 + lq * 8];
#pragma unroll
    for (int nt = 0; nt < 4; ++nt) {
      bf16x8 b = *(const bf16x8*)&WT[(size_t)(bn + nt * 16 + ln) * K + k0 + lq * 8];
      acc[0][nt] = __builtin_amdgcn_mfma_f32_16x16x32_bf16(a0, b, acc[0][nt], 0, 0, 0);
      acc[1][nt] = __builtin_amdgcn_mfma_f32_16x16x32_bf16(a1, b, acc[1][nt], 0, 0, 0);
    }
  }
#pragma unroll
  for (int g = 0; g < 2; ++g) {
    int rowbase = bm + w * 32 + g * 16 + lq * 4;
#pragma unroll
    for (int nt = 0; nt < 4; ++nt) {
      int gn = bn + nt * 16 + ln;
      float bv = bias ? bias[gn] : 0.f;
#pragma unroll
      for (int r = 0; r < 4; ++r) {
        int gm = rowbase + r;
        if (gm < M) {
          float val = acc[g][nt][r] + bv;
          if (OUT_BF16) ((u16*)Y)[(size_t)gm * N + gn] = f2bf(val);
          else          ((float*)Y)[(size_t)gm * N + gn] = val;
        }
      }
    }
  }
}

// ---------------- weight composition (fp32) ----------------------------------
__global__ __launch_bounds__(256) void compose_kernel(
    const float* __restrict__ Wv, const float* __restrict__ We,
    const float* __restrict__ Wmu, float* __restrict__ WP12,
    float* __restrict__ WPe) {
  const int z = blockIdx.z;
  const float* Ap; const float* Bp; float* Cp; int ldc;
  if (z < 4) {
    int part = z >> 1, h = z & 1;
    Ap = Wv + h * 128; Bp = Wmu + part * 128 * 384;
    Cp = WP12 + part * 768 + h * 384; ldc = 1536;
  } else {
    int h = z - 4;
    Ap = We + h * 128; Bp = Wmu + 256 * 384;
    Cp = WPe + h * 384; ldc = 768;
  }
  __shared__ float As[16][68];
  __shared__ float Bs[16][65];
  const int tid = threadIdx.x;
  const int bm = blockIdx.y * 64, bn = blockIdx.x * 64;
  const int tx = tid & 15, ty = tid >> 4;
  float acc[4][4] = {};
  for (int k0 = 0; k0 < 128; k0 += 16) {
#pragma unroll
    for (int i = 0; i < 4; ++i) {
      int l = tid + i * 256;
      int kk = l & 15, m = l >> 4;
      As[kk][m] = Ap[(size_t)(bm + m) * 256 + k0 + kk];
    }
#pragma unroll
    for (int i = 0; i < 4; ++i) {
      int l = tid + i * 256;
      int n = l & 63, kk = l >> 6;
      Bs[kk][n] = Bp[(size_t)(k0 + kk) * 384 + bn + n];
    }
    __syncthreads();
#pragma unroll
    for (int kk = 0; kk < 16; ++kk) {
      float a[4], b[4];
#pragma unroll
      for (int i = 0; i < 4; ++i) a[i] = As[kk][ty * 4 + i];
#pragma unroll
      for (int j = 0; j < 4; ++j) b[j] = Bs[kk][tx * 4 + j];
#pragma unroll
      for (int i = 0; i < 4; ++i)
#pragma unroll
        for (int j = 0; j < 4; ++j) acc[i][j] += a[i] * b[j];
    }
    __syncthreads();
  }
#pragma unroll
  for (int i = 0; i < 4; ++i)
#pragma unroll
    for (int j = 0; j < 4; ++j)
      Cp[(size_t)(bm + ty * 4 + i) * ldc + bn + tx * 4 + j] = acc[i][j];
}

__global__ void cb_kernel(const float* __restrict__ bmu, const float* __restrict__ bv,
                          const float* __restrict__ Wmu, float* __restrict__ cb) {
  int j = blockIdx.x * blockDim.x + threadIdx.x;
  if (j >= 768) return;
  int h = j / 384, g = j - h * 384;
  float s = bmu[g];
  for (int d = 0; d < 128; ++d)
    s += bv[h * 128 + d] * (Wmu[(size_t)d * 384 + g] + Wmu[(size_t)(128 + d) * 384 + g]);
  cb[j] = s;
}

// ---------------- bf16 pack kernels -----------------------------------------
__global__ void pack_bf16_kernel(const float* __restrict__ A, u16* __restrict__ B, int n) {
  int idx = blockIdx.x * blockDim.x + threadIdx.x;
  if (idx < n) B[idx] = f2bf(A[idx]);
}

// WT[n][k] = W[k][n], bf16
__global__ void packT_bf16_kernel(const float* __restrict__ W, u16* __restrict__ WT,
                                  int K, int N) {
  int idx = blockIdx.x * blockDim.x + threadIdx.x;
  if (idx >= K * N) return;
  int n = idx / K, kk = idx - n * K;
  WT[idx] = f2bf(W[(size_t)kk * N + n]);
}

// WcT[col][k], col<256 -> We[k][col], else WPe[k][col-256]
__global__ void pack_wcombT_kernel(const float* __restrict__ We_l,
                                   const float* __restrict__ WPe,
                                   u16* __restrict__ WcT) {
  int idx = blockIdx.x * blockDim.x + threadIdx.x;
  if (idx >= 1024 * 128) return;
  int col = idx >> 7, kk = idx & 127;
  float v = (col < 256) ? We_l[(size_t)kk * 256 + col]
                        : WPe[(size_t)kk * 768 + (col - 256)];
  WcT[idx] = f2bf(v);
}

// WmT[n][k] = Wm[k][n]
__global__ void pack_wmT_kernel(const float* __restrict__ Wm_l, u16* __restrict__ WmT) {
  int idx = blockIdx.x * blockDim.x + threadIdx.x;
  if (idx >= 128 * 384) return;
  int n = idx / 384, kk = idx - n * 384;
  WmT[idx] = f2bf(Wm_l[(size_t)kk * 128 + n]);
}

// ---------------- fused per-edge kernel (MFMA, 8 edges/block) ----------------
//  GEMM1 (MFMA): C1[8][1024] = ef_bf16 @ [We | WPe]  (sea 0..255, Pe 256..1023)
//  Phase A: alpha -> LN384 -> sigmoid gate (all 16 edge-head rows at once)
//  Phase 4: t = Pe + P12[dst] + P12[src] + cb; *gate; -> A2p (bf16, swizzled frag order)
//  GEMM2 (MFMA): m[16][128] = A2 @ WmT; LN128; atomic scatter to agg[dst]
__global__ __launch_bounds__(256, 3) void edge_kernel(
    const u16* __restrict__ qb, const u16* __restrict__ kb,
    const u16* __restrict__ efb, const int* __restrict__ ei,
    const u16* __restrict__ WcT, const u16* __restrict__ P12b,
    const float* __restrict__ cb,
    const float* __restrict__ lag, const float* __restrict__ lab,
    const u16* __restrict__ WmT, const float* __restrict__ bm_l,
    const float* __restrict__ lmg, const float* __restrict__ lmb,
    float* __restrict__ agg, int E) {
  __shared__ __align__(16) u16 C1[8 * 1032];
  __shared__ __align__(16) u16 gate[16 * 392];
  __shared__ __align__(16) u16 A2p[12 * 512];   // aliased as C2 float[16][132] in GEMM2 epilogue
  __shared__ int sid8[8], did8[8];
  float* C2 = (float*)A2p;
  const int tid = threadIdx.x;
  const int e0 = blockIdx.x * 8;
  const int w = tid >> 6, l = tid & 63;
  const int lq = l >> 4, ln = l & 15;
  const float scale = 0.051031036307982884f;  // 1/sqrt(384)

  if (tid < 8) { sid8[tid] = ei[e0 + tid]; did8[tid] = ei[E + e0 + tid]; }

  // ---- GEMM1: rows = 8 edges (A rows 8..15 clamped, outputs dropped) ----
  {
    int er = e0 + ln; if (er > E - 1) er = E - 1;
    bf16x8 afr[4];
    const u16* ab = efb + (size_t)er * 128 + lq * 8;
#pragma unroll
    for (int ks = 0; ks < 4; ++ks) afr[ks] = *(const bf16x8*)(ab + ks * 32);
    for (int nt = 0; nt < 16; ++nt) {
      int g = w * 16 + nt;
      const u16* bb = WcT + (size_t)(g * 16 + ln) * 128 + lq * 8;
      f32x4 acc = {0.f, 0.f, 0.f, 0.f};
#pragma unroll
      for (int ks = 0; ks < 4; ++ks)
        acc = __builtin_amdgcn_mfma_f32_16x16x32_bf16(
            afr[ks], *(const bf16x8*)(bb + ks * 32), acc, 0, 0, 0);
      int col = g * 16 + ln;
      if (lq < 2) {   // only rows 0..7 are real edges
#pragma unroll
        for (int r = 0; r < 4; ++r) C1[(lq * 4 + r) * 1032 + col] = f2bf(acc[r]);
      }
    }
  }
  __syncthreads();

  // ---- Phase A: gate = sigmoid(LN384(alpha)), rows r = h*8+e, 16 lanes/row --
  {
    const int r = tid >> 4, lx = tid & 15;
    const int h = r >> 3, e = r & 7;
    const int dstn = did8[e], srcn = sid8[e];
    const u16* qp  = qb + (size_t)dstn * HCDIM + h * CDIM + lx;
    const u16* kdp = kb + (size_t)dstn * HCDIM + h * CDIM + lx;
    const u16* ksp = kb + (size_t)srcn * HCDIM + h * CDIM + lx;
    const u16* sp = &C1[e * 1032 + h * CDIM + lx];
    float qv[8], al[24], sacc = 0.f, s2acc = 0.f;
#pragma unroll
    for (int j = 0; j < 8; ++j) qv[j] = bf2f(qp[16 * j]);
#pragma unroll
    for (int j = 0; j < 8; ++j) {
      float a = qv[j] * bf2f(kdp[16 * j]) * scale;
      al[j] = a; sacc += a; s2acc += a * a;
    }
#pragma unroll
    for (int j = 0; j < 8; ++j) {
      float a = qv[j] * bf2f(ksp[16 * j]) * scale;
      al[8 + j] = a; sacc += a; s2acc += a * a;
    }
#pragma unroll
    for (int j = 0; j < 8; ++j) {
      float a = qv[j] * bf2f(sp[16 * j]) * scale;
      al[16 + j] = a; sacc += a; s2acc += a * a;
    }
#pragma unroll
    for (int mm = 1; mm < 16; mm <<= 1) {
      sacc += __shfl_xor(sacc, mm); s2acc += __shfl_xor(s2acc, mm);
    }
    float mean = sacc * (1.f / C3DIM);
    float rstd = rsqrtf(s2acc * (1.f / C3DIM) - mean * mean + 1e-5f);
#pragma unroll
    for (int j = 0; j < 24; ++j) {
      int f = (j >> 3) * 128 + lx + 16 * (j & 7);
      float z = (al[j] - mean) * rstd * lag[f] + lab[f];
      gate[r * 392 + f] = f2bf(1.f / (1.f + expf(-z)));
    }
  }
  __syncthreads();

  // ---- Phase 4: t -> A2p (bf16, XOR-swizzled fragment slots) ----
  {
    const int c = tid & 127, hh = tid >> 7;
    const float cb0 = cb[hh * 384 + c];
    const float cb1 = cb[hh * 384 + 128 + c];
    const float cb2 = cb[hh * 384 + 256 + c];
    for (int e = 0; e < 8; ++e) {
      int dstn = did8[e], srcn = sid8[e];
      const u16* pd = P12b + (size_t)dstn * 1536 + hh * 384;
      const u16* ps = P12b + (size_t)srcn * 1536 + 768 + hh * 384;
      const u16* cr = &C1[e * 1032 + 256 + hh * 384];
      const u16* gr = &gate[(hh * 8 + e) * 392];
      int m = hh * 8 + e;
      float t0 = (bf2f(cr[c])       + bf2f(pd[c])       + bf2f(ps[c])       + cb0) * bf2f(gr[c]);
      float t1 = (bf2f(cr[c + 128]) + bf2f(pd[c + 128]) + bf2f(ps[c + 128]) + cb1) * bf2f(gr[c + 128]);
      float t2 = (bf2f(cr[c + 256]) + bf2f(pd[c + 256]) + bf2f(ps[c + 256]) + cb2) * bf2f(gr[c + 256]);
#pragma unroll
      for (int part = 0; part < 3; ++part) {
        int g = c + part * 128;
        float val = part == 0 ? t0 : (part == 1 ? t1 : t2);
        int ks = g >> 5, qq = (g >> 3) & 3, j = g & 7;
        int slot = (m ^ (qq << 1)) | (qq << 4);  // XOR swizzle kills bank conflicts
        A2p[ks * 512 + slot * 8 + j] = f2bf(val);
      }
    }
  }
  __syncthreads();

  // ---- GEMM2: load A2 frags (swizzled), barrier, MFMA, write C2 (aliased) ---
  {
    const int pl = l ^ ((l >> 4) << 1);
    bf16x8 af2[12];
#pragma unroll
    for (int ks = 0; ks < 12; ++ks)
      af2[ks] = *(const bf16x8*)&A2p[ks * 512 + pl * 8];
    __syncthreads();  // all reads of A2p complete before aliased C2 writes
#pragma unroll
    for (int nt = 0; nt < 2; ++nt) {
      int g = w * 2 + nt;
      const u16* bb = WmT + (size_t)(g * 16 + ln) * 384 + lq * 8;
      f32x4 acc = {0.f, 0.f, 0.f, 0.f};
#pragma unroll
      for (int ks = 0; ks < 12; ++ks)
        acc = __builtin_amdgcn_mfma_f32_16x16x32_bf16(
            af2[ks], *(const bf16x8*)(bb + ks * 32), acc, 0, 0, 0);
      int col = g * 16 + ln;
      float bcol = bm_l[col];
#pragma unroll
      for (int r = 0; r < 4; ++r) C2[(lq * 4 + r) * 132 + col] = acc[r] + bcol;
    }
  }
  __syncthreads();

  // ---- LN128 + scatter ----
  {
    for (int rw = w; rw < 16; rw += 4) {
      float v0 = C2[rw * 132 + l], v1 = C2[rw * 132 + l + 64];
      float sa = v0 + v1, s2a = v0 * v0 + v1 * v1;
#pragma unroll
      for (int off2 = 32; off2 > 0; off2 >>= 1) {
        sa += __shfl_down(sa, off2); s2a += __shfl_down(s2a, off2);
      }
      sa = __shfl(sa, 0); s2a = __shfl(s2a, 0);
      float mean = sa * (1.f / CDIM);
      float rstd = rsqrtf(s2a * (1.f / CDIM) - mean * mean + 1e-5f);
      int h = rw >> 3, e = rw & 7;
      int dstn = did8[e];
      float o0 = (v0 - mean) * rstd * lmg[l] + lmb[l];
      float o1 = (v1 - mean) * rstd * lmg[l + 64] + lmb[l + 64];
      atomicAdd(&agg[(size_t)dstn * HCDIM + h * CDIM + l], o0);
      atomicAdd(&agg[(size_t)dstn * HCDIM + h * CDIM + l + 64], o1);
    }
  }
}

// ---------------- BN statistics ---------------------------------------------
__global__ __launch_bounds__(256) void bn_stats_kernel(
    const float* __restrict__ o, float* __restrict__ mu, float* __restrict__ rstd) {
  int c = blockIdx.x, tid = threadIdx.x;
  float s = 0.f, s2 = 0.f;
  for (int r = tid; r < N_NODES; r += 256) {
    float x = o[(size_t)r * CDIM + c];
    s += x; s2 += x * x;
  }
  __shared__ float red[8];
#pragma unroll
  for (int off = 32; off > 0; off >>= 1) {
    s += __shfl_down(s, off); s2 += __shfl_down(s2, off);
  }
  if ((tid & 63) == 0) { red[tid >> 6] = s; red[4 + (tid >> 6)] = s2; }
  __syncthreads();
  if (tid == 0) {
    float ts = red[0] + red[1] + red[2] + red[3];
    float t2 = red[4] + red[5] + red[6] + red[7];
    float m = ts * (1.f / N_NODES);
    float var = t2 * (1.f / N_NODES) - m * m;
    mu[c] = m;
    rstd[c] = rsqrtf(var + 1e-5f);
  }
}

__global__ void bn_silu_skip_kernel(
    const float* __restrict__ o, const float* __restrict__ skip,
    const float* __restrict__ mu, const float* __restrict__ rstd,
    const float* __restrict__ g, const float* __restrict__ b,
    float* __restrict__ nf) {
  int idx = blockIdx.x * blockDim.x + threadIdx.x;
  if (idx >= N_NODES * CDIM) return;
  int c = idx & (CDIM - 1);
  float x = (o[idx] - mu[c]) * rstd[c] * g[c] + b[c];
  float sig = 1.f / (1.f + expf(-x));
  nf[idx] = x * sig + skip[idx];
}

__global__ void pool_kernel(const float* __restrict__ nf, const int* __restrict__ batch,
                            float* __restrict__ psum, float* __restrict__ cnt) {
  int idx = blockIdx.x * blockDim.x + threadIdx.x;
  if (idx >= N_NODES * CDIM) return;
  int n = idx >> 7, c = idx & 127;
  int b = batch[n];
  atomicAdd(&psum[b * CDIM + c], nf[idx]);
  if (c == 0) atomicAdd(&cnt[b], 1.f);
}

__global__ void feats_kernel(const float* __restrict__ psum, const float* __restrict__ cnt,
                             const float* __restrict__ pge, const float* __restrict__ cse,
                             float* __restrict__ feats) {
  int idx = blockIdx.x * blockDim.x + threadIdx.x;
  if (idx >= N_GRAPH * 167) return;
  int b = idx / 167, j = idx - b * 167;
  float val;
  if (j < 128)      val = psum[b * CDIM + j] / fmaxf(cnt[b], 1.f);
  else if (j < 160) val = pge[b * 32 + (j - 128)];
  else              val = cse[b * 7 + (j - 160)];
  feats[idx] = val;
}

__global__ __launch_bounds__(256) void out_kernel(
    const float* __restrict__ h, const float* __restrict__ ow,
    const float* __restrict__ ob, float* __restrict__ out) {
  int b = blockIdx.x, tid = threadIdx.x;
  float s = h[b * 512 + tid] * ow[tid] + h[b * 512 + tid + 256] * ow[tid + 256];
  __shared__ float red[4];
#pragma unroll
  for (int off = 32; off > 0; off >>= 1) s += __shfl_down(s, off);
  if ((tid & 63) == 0) red[tid >> 6] = s;
  __syncthreads();
  if (tid == 0) out[b] = red[0] + red[1] + red[2] + red[3] + ob[0];
}

// ---------------- launch -----------------------------------------------------
extern "C" void kernel_launch(void* const* d_in, const int* in_sizes, int n_in,
                              void* d_out, int out_size, void* d_ws, size_t ws_size,
                              hipStream_t stream) {
  const float* x         = (const float*)d_in[0];
  const float* edge_attr = (const float*)d_in[1];
  const float* pge       = (const float*)d_in[2];
  const float* cse       = (const float*)d_in[3];
  const int*   ei        = (const int*)d_in[4];
  const int*   batch     = (const int*)d_in[5];
  const float* atom_W    = (const float*)d_in[6];
  const float* atom_b    = (const float*)d_in[7];
  const float* edge_W    = (const float*)d_in[8];
  const float* edge_b    = (const float*)d_in[9];
  const float* Wq        = (const float*)d_in[10];
  const float* bq        = (const float*)d_in[11];
  const float* Wk        = (const float*)d_in[12];
  const float* bk        = (const float*)d_in[13];
  const float* Wv        = (const float*)d_in[14];
  const float* bv        = (const float*)d_in[15];
  const float* We        = (const float*)d_in[16];
  const float* Wmu       = (const float*)d_in[17];
  const float* bmu       = (const float*)d_in[18];
  const float* Wm        = (const float*)d_in[19];
  const float* bm        = (const float*)d_in[20];
  const float* ln_m_g    = (const float*)d_in[21];
  const float* ln_m_b    = (const float*)d_in[22];
  const float* ln_a_g    = (const float*)d_in[23];
  const float* ln_a_b    = (const float*)d_in[24];
  const float* Wc        = (const float*)d_in[25];
  const float* bc        = (const float*)d_in[26];
  const float* bn_g      = (const float*)d_in[27];
  const float* bn_b      = (const float*)d_in[28];
  const float* Wskip     = (const float*)d_in[29];
  const float* bskip     = (const float*)d_in[30];
  const float* fc_W      = (const float*)d_in[31];
  const float* fc_b      = (const float*)d_in[32];
  const float* out_W     = (const float*)d_in[33];
  const float* out_b     = (const float*)d_in[34];

  float* ws = (float*)d_ws;
  size_t off = 0;
  float* nf    = ws + off; off += (size_t)N_NODES * CDIM;
  float* ef    = ws + off; off += (size_t)N_EDGES * CDIM;
  float* agg   = ws + off; off += (size_t)N_NODES * HCDIM;
  float* o     = ws + off; off += (size_t)N_NODES * CDIM;
  float* skip  = ws + off; off += (size_t)N_NODES * CDIM;
  float* WP12  = ws + off; off += (size_t)128 * 1536;
  float* WPe   = ws + off; off += (size_t)128 * 768;
  float* cbv   = ws + off; off += 768;
  float* mu    = ws + off; off += CDIM;
  float* rstd  = ws + off; off += CDIM;
  float* psum  = ws + off; off += (size_t)N_GRAPH * CDIM;
  float* cnt   = ws + off; off += N_GRAPH;
  float* feats = ws + off; off += (size_t)N_GRAPH * 167;
  float* h     = ws + off; off += (size_t)N_GRAPH * 512;
  u16* efb   = (u16*)(ws + off); off += (size_t)N_EDGES * 64;     // E*128 u16
  u16* WcT   = (u16*)(ws + off); off += 65536;                    // 1024*128 u16
  u16* WmTb  = (u16*)(ws + off); off += 24576;                    // 128*384 u16
  u16* nfb   = (u16*)(ws + off); off += (size_t)N_NODES * 64;     // N*128 u16
  u16* aggb  = (u16*)(ws + off); off += (size_t)N_NODES * 128;    // N*256 u16
  u16* qbb   = (u16*)(ws + off); off += (size_t)N_NODES * 128;    // N*256 u16
  u16* kbb   = (u16*)(ws + off); off += (size_t)N_NODES * 128;    // N*256 u16
  u16* P12b  = (u16*)(ws + off); off += (size_t)N_NODES * 768;    // N*1536 u16
  u16* WqT   = (u16*)(ws + off); off += 16384;                    // 256*128 u16
  u16* WkT   = (u16*)(ws + off); off += 16384;
  u16* WP12T = (u16*)(ws + off); off += 98304;                    // 1536*128 u16
  u16* WcTw  = (u16*)(ws + off); off += 16384;                    // 128*256 u16
  u16* WskT  = (u16*)(ws + off); off += 8192;                     // 128*128 u16

  auto gemm = [&](const float* A, const float* W, const float* bias, float* Y,
                  int M, int K, int Nn, int act) {
    dim3 grid((Nn + 63) / 64, (M + 63) / 64);
    if (act) gemm_kernel<1><<<grid, 256, 0, stream>>>(A, W, bias, Y, M, K, Nn);
    else     gemm_kernel<0><<<grid, 256, 0, stream>>>(A, W, bias, Y, M, K, Nn);
  };
  auto mgemm = [&](const u16* Ab, const u16* WT, const float* bias, void* Y,
                   int M, int K, int Nn, int out_bf16) {
    dim3 grid(Nn / 64, (M + 127) / 128);
    if (out_bf16) mfma_gemm_kernel<1><<<grid, 256, 0, stream>>>(Ab, WT, bias, Y, M, K, Nn);
    else          mfma_gemm_kernel<0><<<grid, 256, 0, stream>>>(Ab, WT, bias, Y, M, K, Nn);
  };
  auto packT = [&](const float* W, u16* WT, int K, int Nn) {
    packT_bf16_kernel<<<dim3((K * Nn + 255) / 256), dim3(256), 0, stream>>>(W, WT, K, Nn);
  };

  gemm(x, atom_W, atom_b, nf, N_NODES, 92, CDIM, 0);
  gemm(edge_attr, edge_W, edge_b, ef, N_EDGES, 50, CDIM, 0);
  pack_bf16_kernel<<<dim3((N_EDGES * 128) / 256), dim3(256), 0, stream>>>(ef, efb, N_EDGES * 128);

  for (int i = 0; i < 2; ++i) {
    const float* Wv_i  = Wv + (size_t)i * CDIM * HCDIM;
    const float* We_i  = We + (size_t)i * CDIM * HCDIM;
    const float* Wmu_i = Wmu + (size_t)i * C3DIM * C3DIM;
    compose_kernel<<<dim3(6, 2, 6), 256, 0, stream>>>(Wv_i, We_i, Wmu_i, WP12, WPe);
    cb_kernel<<<dim3(3), dim3(256), 0, stream>>>(bmu + i * C3DIM, bv + i * HCDIM, Wmu_i, cbv);
    pack_wcombT_kernel<<<dim3(512), dim3(256), 0, stream>>>(We_i, WPe, WcT);
    pack_wmT_kernel<<<dim3(192), dim3(256), 0, stream>>>(Wm + (size_t)i * C3DIM * CDIM, WmTb);
    packT(Wq + (size_t)i * CDIM * HCDIM, WqT, CDIM, HCDIM);
    packT(Wk + (size_t)i * CDIM * HCDIM, WkT, CDIM, HCDIM);
    packT(WP12, WP12T, CDIM, 1536);
    packT(Wc + (size_t)i * HCDIM * CDIM, WcTw, HCDIM, CDIM);
    packT(Wskip + (size_t)i * CDIM * CDIM, WskT, CDIM, CDIM);
    pack_bf16_kernel<<<dim3((N_NODES * 128 + 255) / 256), dim3(256), 0, stream>>>(nf, nfb, N_NODES * 128);

    mgemm(nfb, WqT, bq + i * HCDIM, qbb, N_NODES, CDIM, HCDIM, 1);
    mgemm(nfb, WkT, bk + i * HCDIM, kbb, N_NODES, CDIM, HCDIM, 1);
    mgemm(nfb, WP12T, nullptr, P12b, N_NODES, CDIM, 1536, 1);
    hipMemsetAsync(agg, 0, (size_t)N_NODES * HCDIM * sizeof(float), stream);
    edge_kernel<<<dim3(N_EDGES / 8), dim3(256), 0, stream>>>(
        qbb, kbb, efb, ei, WcT, P12b, cbv,
        ln_a_g + i * C3DIM, ln_a_b + i * C3DIM,
        WmTb, bm + i * CDIM,
        ln_m_g + i * CDIM, ln_m_b + i * CDIM, agg, N_EDGES);
    pack_bf16_kernel<<<dim3((N_NODES * 256 + 255) / 256), dim3(256), 0, stream>>>(agg, aggb, N_NODES * 256);
    mgemm(aggb, WcTw, bc + i * CDIM, o, N_NODES, HCDIM, CDIM, 0);
    bn_stats_kernel<<<dim3(CDIM), dim3(256), 0, stream>>>(o, mu, rstd);
    mgemm(nfb, WskT, bskip + i * CDIM, skip, N_NODES, CDIM, CDIM, 0);
    bn_silu_skip_kernel<<<dim3((N_NODES * CDIM + 255) / 256), dim3(256), 0, stream>>>(
        o, skip, mu, rstd, bn_g + i * CDIM, bn_b + i * CDIM, nf);
  }

  hipMemsetAsync(psum, 0, (size_t)(N_GRAPH * CDIM + N_GRAPH) * sizeof(float), stream);
  pool_kernel<<<dim3((N_NODES * CDIM + 255) / 256), dim3(256), 0, stream>>>(nf, batch, psum, cnt);
  feats_kernel<<<dim3((N_GRAPH * 167 + 255) / 256), dim3(256), 0, stream>>>(psum, cnt, pge, cse, feats);
  gemm(feats, fc_W, fc_b, h, N_GRAPH, 167, 512, 1);
  out_kernel<<<dim3(N_GRAPH), dim3(256), 0, stream>>>(h, out_W, out_b, (float*)d_out);
}

// Round 5
// 1492.826 us; speedup vs baseline: 1.2071x; 1.2071x over previous
//
#include <hip/hip_runtime.h>
#include <math.h>

#define N_NODES 10000
#define N_EDGES 100000
#define N_GRAPH 64
#define CDIM 128
#define HCDIM 256
#define C3DIM 384

typedef unsigned short u16;
typedef __attribute__((ext_vector_type(8))) short bf16x8;
typedef __attribute__((ext_vector_type(4))) float f32x4;

__device__ __forceinline__ u16 f2bf(float f) {
  union { float f; unsigned int u; } x; x.f = f;
  unsigned int u = x.u + 0x7fffu + ((x.u >> 16) & 1u);
  return (u16)(u >> 16);
}
__device__ __forceinline__ float bf2f(u16 h) {
  union { unsigned int u; float f; } x; x.u = ((unsigned int)h) << 16;
  return x.f;
}

// ---------------- generic fp32 GEMM (small/odd-K cases) ----------------------
template<int ACT>
__global__ __launch_bounds__(256) void gemm_kernel(
    const float* __restrict__ A, const float* __restrict__ W,
    const float* __restrict__ bias, float* __restrict__ Y,
    int M, int K, int N) {
  __shared__ float As[16][68];
  __shared__ float Bs[16][65];
  const int tid = threadIdx.x;
  const int bm = blockIdx.y * 64, bn = blockIdx.x * 64;
  const int tx = tid & 15, ty = tid >> 4;
  float acc[4][4] = {};
  for (int k0 = 0; k0 < K; k0 += 16) {
#pragma unroll
    for (int i = 0; i < 4; ++i) {
      int l = tid + i * 256;
      int kk = l & 15, m = l >> 4;
      int gm = bm + m, gk = k0 + kk;
      As[kk][m] = (gm < M && gk < K) ? A[(size_t)gm * K + gk] : 0.f;
    }
#pragma unroll
    for (int i = 0; i < 4; ++i) {
      int l = tid + i * 256;
      int n = l & 63, kk = l >> 6;
      int gk = k0 + kk, gn = bn + n;
      Bs[kk][n] = (gk < K && gn < N) ? W[(size_t)gk * N + gn] : 0.f;
    }
    __syncthreads();
#pragma unroll
    for (int kk = 0; kk < 16; ++kk) {
      float a[4], b[4];
#pragma unroll
      for (int i = 0; i < 4; ++i) a[i] = As[kk][ty * 4 + i];
#pragma unroll
      for (int j = 0; j < 4; ++j) b[j] = Bs[kk][tx * 4 + j];
#pragma unroll
      for (int i = 0; i < 4; ++i)
#pragma unroll
        for (int j = 0; j < 4; ++j) acc[i][j] += a[i] * b[j];
    }
    __syncthreads();
  }
#pragma unroll
  for (int i = 0; i < 4; ++i) {
    int gm = bm + ty * 4 + i;
    if (gm >= M) continue;
#pragma unroll
    for (int j = 0; j < 4; ++j) {
      int gn = bn + tx * 4 + j;
      if (gn >= N) continue;
      float val = acc[i][j] + (bias ? bias[gn] : 0.f);
      if (ACT == 1) val = val / (1.f + expf(-val));
      Y[(size_t)gm * N + gn] = val;
    }
  }
}

// ---------------- MFMA dense GEMM: Y[M,N] = Ab[M,K] @ WT[N,K]^T (+bias) ------
template<int OUT_BF16>
__global__ __launch_bounds__(256) void mfma_gemm_kernel(
    const u16* __restrict__ Ab, const u16* __restrict__ WT,
    const float* __restrict__ bias, void* __restrict__ Y,
    int M, int K, int N) {
  const int tid = threadIdx.x;
  const int w = tid >> 6, l = tid & 63;
  const int lq = l >> 4, ln = l & 15;
  const int bm = blockIdx.y * 128, bn = blockIdx.x * 64;
  int ra = bm + w * 32 + ln;      if (ra > M - 1) ra = M - 1;
  int rb = bm + w * 32 + 16 + ln; if (rb > M - 1) rb = M - 1;
  f32x4 acc[2][4];
#pragma unroll
  for (int g = 0; g < 2; ++g)
#pragma unroll
    for (int nt = 0; nt < 4; ++nt) acc[g][nt] = {0.f, 0.f, 0.f, 0.f};
  for (int k0 = 0; k0 < K; k0 += 32) {
    bf16x8 a0 = *(const bf16x8*)&Ab[(size_t)ra * K + k0 + lq * 8];
    bf16x8 a1 = *(const bf16x8*)&Ab[(size_t)rb * K + k0 + lq * 8];
#pragma unroll
    for (int nt = 0; nt < 4; ++nt) {
      bf16x8 b = *(const bf16x8*)&WT[(size_t)(bn + nt * 16 + ln) * K + k0 + lq * 8];
      acc[0][nt] = __builtin_amdgcn_mfma_f32_16x16x32_bf16(a0, b, acc[0][nt], 0, 0, 0);
      acc[1][nt] = __builtin_amdgcn_mfma_f32_16x16x32_bf16(a1, b, acc[1][nt], 0, 0, 0);
    }
  }
#pragma unroll
  for (int g = 0; g < 2; ++g) {
    int rowbase = bm + w * 32 + g * 16 + lq * 4;
#pragma unroll
    for (int nt = 0; nt < 4; ++nt) {
      int gn = bn + nt * 16 + ln;
      float bv = bias ? bias[gn] : 0.f;
#pragma unroll
      for (int r = 0; r < 4; ++r) {
        int gm = rowbase + r;
        if (gm < M) {
          float val = acc[g][nt][r] + bv;
          if (OUT_BF16) ((u16*)Y)[(size_t)gm * N + gn] = f2bf(val);
          else          ((float*)Y)[(size_t)gm * N + gn] = val;
        }
      }
    }
  }
}

// ---------------- weight composition (fp32) ----------------------------------
__global__ __launch_bounds__(256) void compose_kernel(
    const float* __restrict__ Wv, const float* __restrict__ We,
    const float* __restrict__ Wmu, float* __restrict__ WP12,
    float* __restrict__ WPe) {
  const int z = blockIdx.z;
  const float* Ap; const float* Bp; float* Cp; int ldc;
  if (z < 4) {
    int part = z >> 1, h = z & 1;
    Ap = Wv + h * 128; Bp = Wmu + part * 128 * 384;
    Cp = WP12 + part * 768 + h * 384; ldc = 1536;
  } else {
    int h = z - 4;
    Ap = We + h * 128; Bp = Wmu + 256 * 384;
    Cp = WPe + h * 384; ldc = 768;
  }
  __shared__ float As[16][68];
  __shared__ float Bs[16][65];
  const int tid = threadIdx.x;
  const int bm = blockIdx.y * 64, bn = blockIdx.x * 64;
  const int tx = tid & 15, ty = tid >> 4;
  float acc[4][4] = {};
  for (int k0 = 0; k0 < 128; k0 += 16) {
#pragma unroll
    for (int i = 0; i < 4; ++i) {
      int l = tid + i * 256;
      int kk = l & 15, m = l >> 4;
      As[kk][m] = Ap[(size_t)(bm + m) * 256 + k0 + kk];
    }
#pragma unroll
    for (int i = 0; i < 4; ++i) {
      int l = tid + i * 256;
      int n = l & 63, kk = l >> 6;
      Bs[kk][n] = Bp[(size_t)(k0 + kk) * 384 + bn + n];
    }
    __syncthreads();
#pragma unroll
    for (int kk = 0; kk < 16; ++kk) {
      float a[4], b[4];
#pragma unroll
      for (int i = 0; i < 4; ++i) a[i] = As[kk][ty * 4 + i];
#pragma unroll
      for (int j = 0; j < 4; ++j) b[j] = Bs[kk][tx * 4 + j];
#pragma unroll
      for (int i = 0; i < 4; ++i)
#pragma unroll
        for (int j = 0; j < 4; ++j) acc[i][j] += a[i] * b[j];
    }
    __syncthreads();
  }
#pragma unroll
  for (int i = 0; i < 4; ++i)
#pragma unroll
    for (int j = 0; j < 4; ++j)
      Cp[(size_t)(bm + ty * 4 + i) * ldc + bn + tx * 4 + j] = acc[i][j];
}

__global__ void cb_kernel(const float* __restrict__ bmu, const float* __restrict__ bv,
                          const float* __restrict__ Wmu, float* __restrict__ cb) {
  int j = blockIdx.x * blockDim.x + threadIdx.x;
  if (j >= 768) return;
  int h = j / 384, g = j - h * 384;
  float s = bmu[g];
  for (int d = 0; d < 128; ++d)
    s += bv[h * 128 + d] * (Wmu[(size_t)d * 384 + g] + Wmu[(size_t)(128 + d) * 384 + g]);
  cb[j] = s;
}

// ---------------- bf16 pack kernels -----------------------------------------
__global__ void pack_bf16_kernel(const float* __restrict__ A, u16* __restrict__ B, int n) {
  int idx = blockIdx.x * blockDim.x + threadIdx.x;
  if (idx < n) B[idx] = f2bf(A[idx]);
}

__global__ void packT_bf16_kernel(const float* __restrict__ W, u16* __restrict__ WT,
                                  int K, int N) {
  int idx = blockIdx.x * blockDim.x + threadIdx.x;
  if (idx >= K * N) return;
  int n = idx / K, kk = idx - n * K;
  WT[idx] = f2bf(W[(size_t)kk * N + n]);
}

__global__ void pack_wcombT_kernel(const float* __restrict__ We_l,
                                   const float* __restrict__ WPe,
                                   u16* __restrict__ WcT) {
  int idx = blockIdx.x * blockDim.x + threadIdx.x;
  if (idx >= 1024 * 128) return;
  int col = idx >> 7, kk = idx & 127;
  float v = (col < 256) ? We_l[(size_t)kk * 256 + col]
                        : WPe[(size_t)kk * 768 + (col - 256)];
  WcT[idx] = f2bf(v);
}

__global__ void pack_wmT_kernel(const float* __restrict__ Wm_l, u16* __restrict__ WmT) {
  int idx = blockIdx.x * blockDim.x + threadIdx.x;
  if (idx >= 128 * 384) return;
  int n = idx / 384, kk = idx - n * 384;
  WmT[idx] = f2bf(Wm_l[(size_t)kk * 128 + n]);
}

// ---------------- fused per-edge kernel (MFMA, 16 edges/block, prefetch) -----
// Entry: prefetch ALL phase-A gathers (q/kd/ks, bf16x8) and phase-4 gathers
// (P12 dst/src slices, bf16x8) into registers, then GEMM1 overlaps them.
//  GEMM1 (MFMA): C1[16][1024] = ef_bf16 @ [We | WPe]
//  2 sub-batches of 8 edges (rows r = h*8+e):
//   Phase A: alpha -> LN384 -> sigmoid gate (registers + C1 sea)
//   Phase 4: t = Pe + P12d + P12s + cb; *gate; -> A2p (bf16, swizzled frags)
//   GEMM2 (MFMA): m[16][128] = A2 @ WmT; LN128; atomic scatter to agg[dst]
__global__ __launch_bounds__(256, 2) void edge_kernel(
    const u16* __restrict__ qb, const u16* __restrict__ kb,
    const u16* __restrict__ efb, const int* __restrict__ ei,
    const u16* __restrict__ WcT, const u16* __restrict__ P12b,
    const float* __restrict__ cb,
    const float* __restrict__ lag, const float* __restrict__ lab,
    const u16* __restrict__ WmT, const float* __restrict__ bm_l,
    const float* __restrict__ lmg, const float* __restrict__ lmb,
    float* __restrict__ agg, int E) {
  __shared__ __align__(16) u16 C1[16 * 1032];
  __shared__ __align__(16) u16 gate[16 * 392];
  __shared__ __align__(16) u16 A2p[12 * 512];   // aliased as C2 float[16][132]
  __shared__ int did16[16];
  float* C2 = (float*)A2p;
  const int tid = threadIdx.x;
  const int e0 = blockIdx.x * 16;
  const int w = tid >> 6, l = tid & 63;
  const int lq = l >> 4, ln = l & 15;
  const float scale = 0.051031036307982884f;  // 1/sqrt(384)

  if (tid < 16) did16[tid] = ei[E + e0 + tid];

  // ---- Prefetch Phase-A gathers (both sub-batches) ----
  const int rA = tid >> 4, lx = tid & 15;
  const int hA = rA >> 3, eA = rA & 7;
  bf16x8 qv[2], kdv[2], ksv[2];
#pragma unroll
  for (int s = 0; s < 2; ++s) {
    int edge = e0 + s * 8 + eA;
    int dstn = ei[E + edge], srcn = ei[edge];
    qv[s]  = *(const bf16x8*)&qb[(size_t)dstn * HCDIM + hA * CDIM + lx * 8];
    kdv[s] = *(const bf16x8*)&kb[(size_t)dstn * HCDIM + hA * CDIM + lx * 8];
    ksv[s] = *(const bf16x8*)&kb[(size_t)srcn * HCDIM + hA * CDIM + lx * 8];
  }

  // ---- Prefetch Phase-4 gathers (both sub-batches) ----
  const int g4 = tid >> 3, lane4 = tid & 7;
  const int r4 = g4 & 15, half4 = g4 >> 4;
  const int h4 = r4 >> 3, e4 = r4 & 7;
  const int base4 = half4 * 192;
  bf16x8 pdv[2][3], psv[2][3];
#pragma unroll
  for (int s = 0; s < 2; ++s) {
    int edge = e0 + s * 8 + e4;
    int dstn = ei[E + edge], srcn = ei[edge];
    const u16* pd = P12b + (size_t)dstn * 1536 + h4 * 384 + base4 + lane4 * 8;
    const u16* ps = P12b + (size_t)srcn * 1536 + 768 + h4 * 384 + base4 + lane4 * 8;
#pragma unroll
    for (int o = 0; o < 3; ++o) {
      pdv[s][o] = *(const bf16x8*)(pd + o * 64);
      psv[s][o] = *(const bf16x8*)(ps + o * 64);
    }
  }

  // ---- GEMM1: C1[16][1024] = efb @ WcT ----
  {
    bf16x8 afr[4];
    const u16* ab = efb + (size_t)(e0 + ln) * 128 + lq * 8;
#pragma unroll
    for (int ks = 0; ks < 4; ++ks) afr[ks] = *(const bf16x8*)(ab + ks * 32);
    for (int nt = 0; nt < 16; ++nt) {
      int g = w * 16 + nt;
      const u16* bb = WcT + (size_t)(g * 16 + ln) * 128 + lq * 8;
      f32x4 acc = {0.f, 0.f, 0.f, 0.f};
#pragma unroll
      for (int ks = 0; ks < 4; ++ks)
        acc = __builtin_amdgcn_mfma_f32_16x16x32_bf16(
            afr[ks], *(const bf16x8*)(bb + ks * 32), acc, 0, 0, 0);
      int col = g * 16 + ln;
#pragma unroll
      for (int r = 0; r < 4; ++r) C1[(lq * 4 + r) * 1032 + col] = f2bf(acc[r]);
    }
  }
  __syncthreads();

  for (int s = 0; s < 2; ++s) {
    // ---- Phase A: gate = sigmoid(LN384(alpha)) ----
    {
      bf16x8 eav = *(const bf16x8*)&C1[(s * 8 + eA) * 1032 + hA * CDIM + lx * 8];
      float a0[8], a1[8], a2[8];
      float sacc = 0.f, s2acc = 0.f;
#pragma unroll
      for (int j = 0; j < 8; ++j) {
        float qf = bf2f((u16)qv[s][j]);
        float x0 = qf * bf2f((u16)kdv[s][j]) * scale;
        float x1 = qf * bf2f((u16)ksv[s][j]) * scale;
        float x2 = qf * bf2f((u16)eav[j]) * scale;
        a0[j] = x0; a1[j] = x1; a2[j] = x2;
        sacc += x0 + x1 + x2;
        s2acc += x0 * x0 + x1 * x1 + x2 * x2;
      }
#pragma unroll
      for (int mm = 1; mm < 16; mm <<= 1) {
        sacc += __shfl_xor(sacc, mm); s2acc += __shfl_xor(s2acc, mm);
      }
      float mean = sacc * (1.f / C3DIM);
      float rstd = rsqrtf(s2acc * (1.f / C3DIM) - mean * mean + 1e-5f);
#pragma unroll
      for (int part = 0; part < 3; ++part) {
        const float* lg = lag + part * 128 + lx * 8;
        const float* lb = lab + part * 128 + lx * 8;
        f32x4 g0 = *(const f32x4*)lg, g1 = *(const f32x4*)(lg + 4);
        f32x4 b0 = *(const f32x4*)lb, b1 = *(const f32x4*)(lb + 4);
        bf16x8 gv;
#pragma unroll
        for (int j = 0; j < 8; ++j) {
          float av = part == 0 ? a0[j] : (part == 1 ? a1[j] : a2[j]);
          float gg = j < 4 ? g0[j] : g1[j - 4];
          float bb2 = j < 4 ? b0[j] : b1[j - 4];
          float z = (av - mean) * rstd * gg + bb2;
          gv[j] = (short)f2bf(1.f / (1.f + expf(-z)));
        }
        *(bf16x8*)&gate[rA * 392 + part * 128 + lx * 8] = gv;
      }
    }
    __syncthreads();

    // ---- Phase 4: t -> A2p (bf16, swizzled fragment slots) ----
    {
      const u16* pe = &C1[(s * 8 + e4) * 1032 + 256 + h4 * 384 + base4 + lane4 * 8];
      const u16* gt = &gate[r4 * 392 + base4 + lane4 * 8];
#pragma unroll
      for (int o = 0; o < 3; ++o) {
        int c = base4 + lane4 * 8 + o * 64;
        bf16x8 pev = *(const bf16x8*)(pe + o * 64);
        bf16x8 gv  = *(const bf16x8*)(gt + o * 64);
        f32x4 cb0 = *(const f32x4*)&cb[h4 * 384 + c];
        f32x4 cb1 = *(const f32x4*)&cb[h4 * 384 + c + 4];
        bf16x8 outv;
#pragma unroll
        for (int j = 0; j < 8; ++j) {
          float cbj = j < 4 ? cb0[j] : cb1[j - 4];
          float t = (bf2f((u16)pev[j]) + bf2f((u16)pdv[s][o][j]) +
                     bf2f((u16)psv[s][o][j]) + cbj) * bf2f((u16)gv[j]);
          outv[j] = (short)f2bf(t);
        }
        int ks = c >> 5, lqw = (c >> 3) & 3;
        int slot = (((r4 ^ (lqw << 2)) + ks) & 15) | (lqw << 4);
        *(bf16x8*)&A2p[ks * 512 + slot * 8] = outv;
      }
    }
    __syncthreads();

    // ---- GEMM2: load A2 frags (swizzled), barrier, MFMA, write C2 (aliased) -
    {
      bf16x8 af2[12];
#pragma unroll
      for (int ks = 0; ks < 12; ++ks) {
        int slot = (((ln ^ (lq << 2)) + ks) & 15) | (lq << 4);
        af2[ks] = *(const bf16x8*)&A2p[ks * 512 + slot * 8];
      }
      __syncthreads();  // all reads of A2p complete before aliased C2 writes
#pragma unroll
      for (int nt = 0; nt < 2; ++nt) {
        int g = w * 2 + nt;
        const u16* bb = WmT + (size_t)(g * 16 + ln) * 384 + lq * 8;
        f32x4 acc = {0.f, 0.f, 0.f, 0.f};
#pragma unroll
        for (int ks = 0; ks < 12; ++ks)
          acc = __builtin_amdgcn_mfma_f32_16x16x32_bf16(
              af2[ks], *(const bf16x8*)(bb + ks * 32), acc, 0, 0, 0);
        int col = g * 16 + ln;
        float bcol = bm_l[col];
#pragma unroll
        for (int r = 0; r < 4; ++r) C2[(lq * 4 + r) * 132 + col] = acc[r] + bcol;
      }
    }
    __syncthreads();

    // ---- LN128 + scatter ----
    {
      for (int rw = w; rw < 16; rw += 4) {
        float v0 = C2[rw * 132 + l], v1 = C2[rw * 132 + l + 64];
        float sa = v0 + v1, s2a = v0 * v0 + v1 * v1;
#pragma unroll
        for (int off2 = 32; off2 > 0; off2 >>= 1) {
          sa += __shfl_down(sa, off2); s2a += __shfl_down(s2a, off2);
        }
        sa = __shfl(sa, 0); s2a = __shfl(s2a, 0);
        float mean = sa * (1.f / CDIM);
        float rstd = rsqrtf(s2a * (1.f / CDIM) - mean * mean + 1e-5f);
        int h = rw >> 3, e = rw & 7;
        int dstn = did16[s * 8 + e];
        float o0 = (v0 - mean) * rstd * lmg[l] + lmb[l];
        float o1 = (v1 - mean) * rstd * lmg[l + 64] + lmb[l + 64];
        atomicAdd(&agg[(size_t)dstn * HCDIM + h * CDIM + l], o0);
        atomicAdd(&agg[(size_t)dstn * HCDIM + h * CDIM + l + 64], o1);
      }
    }
    __syncthreads();
  }
}

// ---------------- BN statistics ---------------------------------------------
__global__ __launch_bounds__(256) void bn_stats_kernel(
    const float* __restrict__ o, float* __restrict__ mu, float* __restrict__ rstd) {
  int c = blockIdx.x, tid = threadIdx.x;
  float s = 0.f, s2 = 0.f;
  for (int r = tid; r < N_NODES; r += 256) {
    float x = o[(size_t)r * CDIM + c];
    s += x; s2 += x * x;
  }
  __shared__ float red[8];
#pragma unroll
  for (int off = 32; off > 0; off >>= 1) {
    s += __shfl_down(s, off); s2 += __shfl_down(s2, off);
  }
  if ((tid & 63) == 0) { red[tid >> 6] = s; red[4 + (tid >> 6)] = s2; }
  __syncthreads();
  if (tid == 0) {
    float ts = red[0] + red[1] + red[2] + red[3];
    float t2 = red[4] + red[5] + red[6] + red[7];
    float m = ts * (1.f / N_NODES);
    float var = t2 * (1.f / N_NODES) - m * m;
    mu[c] = m;
    rstd[c] = rsqrtf(var + 1e-5f);
  }
}

__global__ void bn_silu_skip_kernel(
    const float* __restrict__ o, const float* __restrict__ skip,
    const float* __restrict__ mu, const float* __restrict__ rstd,
    const float* __restrict__ g, const float* __restrict__ b,
    float* __restrict__ nf) {
  int idx = blockIdx.x * blockDim.x + threadIdx.x;
  if (idx >= N_NODES * CDIM) return;
  int c = idx & (CDIM - 1);
  float x = (o[idx] - mu[c]) * rstd[c] * g[c] + b[c];
  float sig = 1.f / (1.f + expf(-x));
  nf[idx] = x * sig + skip[idx];
}

__global__ void pool_kernel(const float* __restrict__ nf, const int* __restrict__ batch,
                            float* __restrict__ psum, float* __restrict__ cnt) {
  int idx = blockIdx.x * blockDim.x + threadIdx.x;
  if (idx >= N_NODES * CDIM) return;
  int n = idx >> 7, c = idx & 127;
  int b = batch[n];
  atomicAdd(&psum[b * CDIM + c], nf[idx]);
  if (c == 0) atomicAdd(&cnt[b], 1.f);
}

__global__ void feats_kernel(const float* __restrict__ psum, const float* __restrict__ cnt,
                             const float* __restrict__ pge, const float* __restrict__ cse,
                             float* __restrict__ feats) {
  int idx = blockIdx.x * blockDim.x + threadIdx.x;
  if (idx >= N_GRAPH * 167) return;
  int b = idx / 167, j = idx - b * 167;
  float val;
  if (j < 128)      val = psum[b * CDIM + j] / fmaxf(cnt[b], 1.f);
  else if (j < 160) val = pge[b * 32 + (j - 128)];
  else              val = cse[b * 7 + (j - 160)];
  feats[idx] = val;
}

__global__ __launch_bounds__(256) void out_kernel(
    const float* __restrict__ h, const float* __restrict__ ow,
    const float* __restrict__ ob, float* __restrict__ out) {
  int b = blockIdx.x, tid = threadIdx.x;
  float s = h[b * 512 + tid] * ow[tid] + h[b * 512 + tid + 256] * ow[tid + 256];
  __shared__ float red[4];
#pragma unroll
  for (int off = 32; off > 0; off >>= 1) s += __shfl_down(s, off);
  if ((tid & 63) == 0) red[tid >> 6] = s;
  __syncthreads();
  if (tid == 0) out[b] = red[0] + red[1] + red[2] + red[3] + ob[0];
}

// ---------------- launch -----------------------------------------------------
extern "C" void kernel_launch(void* const* d_in, const int* in_sizes, int n_in,
                              void* d_out, int out_size, void* d_ws, size_t ws_size,
                              hipStream_t stream) {
  const float* x         = (const float*)d_in[0];
  const float* edge_attr = (const float*)d_in[1];
  const float* pge       = (const float*)d_in[2];
  const float* cse       = (const float*)d_in[3];
  const int*   ei        = (const int*)d_in[4];
  const int*   batch     = (const int*)d_in[5];
  const float* atom_W    = (const float*)d_in[6];
  const float* atom_b    = (const float*)d_in[7];
  const float* edge_W    = (const float*)d_in[8];
  const float* edge_b    = (const float*)d_in[9];
  const float* Wq        = (const float*)d_in[10];
  const float* bq        = (const float*)d_in[11];
  const float* Wk        = (const float*)d_in[12];
  const float* bk        = (const float*)d_in[13];
  const float* Wv        = (const float*)d_in[14];
  const float* bv        = (const float*)d_in[15];
  const float* We        = (const float*)d_in[16];
  const float* Wmu       = (const float*)d_in[17];
  const float* bmu       = (const float*)d_in[18];
  const float* Wm        = (const float*)d_in[19];
  const float* bm        = (const float*)d_in[20];
  const float* ln_m_g    = (const float*)d_in[21];
  const float* ln_m_b    = (const float*)d_in[22];
  const float* ln_a_g    = (const float*)d_in[23];
  const float* ln_a_b    = (const float*)d_in[24];
  const float* Wc        = (const float*)d_in[25];
  const float* bc        = (const float*)d_in[26];
  const float* bn_g      = (const float*)d_in[27];
  const float* bn_b      = (const float*)d_in[28];
  const float* Wskip     = (const float*)d_in[29];
  const float* bskip     = (const float*)d_in[30];
  const float* fc_W      = (const float*)d_in[31];
  const float* fc_b      = (const float*)d_in[32];
  const float* out_W     = (const float*)d_in[33];
  const float* out_b     = (const float*)d_in[34];

  float* ws = (float*)d_ws;
  size_t off = 0;
  float* nf    = ws + off; off += (size_t)N_NODES * CDIM;
  float* ef    = ws + off; off += (size_t)N_EDGES * CDIM;
  float* agg   = ws + off; off += (size_t)N_NODES * HCDIM;
  float* o     = ws + off; off += (size_t)N_NODES * CDIM;
  float* skip  = ws + off; off += (size_t)N_NODES * CDIM;
  float* WP12  = ws + off; off += (size_t)128 * 1536;
  float* WPe   = ws + off; off += (size_t)128 * 768;
  float* cbv   = ws + off; off += 768;
  float* mu    = ws + off; off += CDIM;
  float* rstd  = ws + off; off += CDIM;
  float* psum  = ws + off; off += (size_t)N_GRAPH * CDIM;
  float* cnt   = ws + off; off += N_GRAPH;
  float* feats = ws + off; off += (size_t)N_GRAPH * 167;
  float* h     = ws + off; off += (size_t)N_GRAPH * 512;
  u16* efb   = (u16*)(ws + off); off += (size_t)N_EDGES * 64;     // E*128 u16
  u16* WcT   = (u16*)(ws + off); off += 65536;                    // 1024*128 u16
  u16* WmTb  = (u16*)(ws + off); off += 24576;                    // 128*384 u16
  u16* nfb   = (u16*)(ws + off); off += (size_t)N_NODES * 64;     // N*128 u16
  u16* aggb  = (u16*)(ws + off); off += (size_t)N_NODES * 128;    // N*256 u16
  u16* qbb   = (u16*)(ws + off); off += (size_t)N_NODES * 128;    // N*256 u16
  u16* kbb   = (u16*)(ws + off); off += (size_t)N_NODES * 128;    // N*256 u16
  u16* P12b  = (u16*)(ws + off); off += (size_t)N_NODES * 768;    // N*1536 u16
  u16* WqT   = (u16*)(ws + off); off += 16384;                    // 256*128 u16
  u16* WkT   = (u16*)(ws + off); off += 16384;
  u16* WP12T = (u16*)(ws + off); off += 98304;                    // 1536*128 u16
  u16* WcTw  = (u16*)(ws + off); off += 16384;                    // 128*256 u16
  u16* WskT  = (u16*)(ws + off); off += 8192;                     // 128*128 u16

  auto gemm = [&](const float* A, const float* W, const float* bias, float* Y,
                  int M, int K, int Nn, int act) {
    dim3 grid((Nn + 63) / 64, (M + 63) / 64);
    if (act) gemm_kernel<1><<<grid, 256, 0, stream>>>(A, W, bias, Y, M, K, Nn);
    else     gemm_kernel<0><<<grid, 256, 0, stream>>>(A, W, bias, Y, M, K, Nn);
  };
  auto mgemm = [&](const u16* Ab, const u16* WT, const float* bias, void* Y,
                   int M, int K, int Nn, int out_bf16) {
    dim3 grid(Nn / 64, (M + 127) / 128);
    if (out_bf16) mfma_gemm_kernel<1><<<grid, 256, 0, stream>>>(Ab, WT, bias, Y, M, K, Nn);
    else          mfma_gemm_kernel<0><<<grid, 256, 0, stream>>>(Ab, WT, bias, Y, M, K, Nn);
  };
  auto packT = [&](const float* W, u16* WT, int K, int Nn) {
    packT_bf16_kernel<<<dim3((K * Nn + 255) / 256), dim3(256), 0, stream>>>(W, WT, K, Nn);
  };

  gemm(x, atom_W, atom_b, nf, N_NODES, 92, CDIM, 0);
  gemm(edge_attr, edge_W, edge_b, ef, N_EDGES, 50, CDIM, 0);
  pack_bf16_kernel<<<dim3((N_EDGES * 128) / 256), dim3(256), 0, stream>>>(ef, efb, N_EDGES * 128);

  for (int i = 0; i < 2; ++i) {
    const float* Wv_i  = Wv + (size_t)i * CDIM * HCDIM;
    const float* We_i  = We + (size_t)i * CDIM * HCDIM;
    const float* Wmu_i = Wmu + (size_t)i * C3DIM * C3DIM;
    compose_kernel<<<dim3(6, 2, 6), 256, 0, stream>>>(Wv_i, We_i, Wmu_i, WP12, WPe);
    cb_kernel<<<dim3(3), dim3(256), 0, stream>>>(bmu + i * C3DIM, bv + i * HCDIM, Wmu_i, cbv);
    pack_wcombT_kernel<<<dim3(512), dim3(256), 0, stream>>>(We_i, WPe, WcT);
    pack_wmT_kernel<<<dim3(192), dim3(256), 0, stream>>>(Wm + (size_t)i * C3DIM * CDIM, WmTb);
    packT(Wq + (size_t)i * CDIM * HCDIM, WqT, CDIM, HCDIM);
    packT(Wk + (size_t)i * CDIM * HCDIM, WkT, CDIM, HCDIM);
    packT(WP12, WP12T, CDIM, 1536);
    packT(Wc + (size_t)i * HCDIM * CDIM, WcTw, HCDIM, CDIM);
    packT(Wskip + (size_t)i * CDIM * CDIM, WskT, CDIM, CDIM);
    pack_bf16_kernel<<<dim3((N_NODES * 128 + 255) / 256), dim3(256), 0, stream>>>(nf, nfb, N_NODES * 128);

    mgemm(nfb, WqT, bq + i * HCDIM, qbb, N_NODES, CDIM, HCDIM, 1);
    mgemm(nfb, WkT, bk + i * HCDIM, kbb, N_NODES, CDIM, HCDIM, 1);
    mgemm(nfb, WP12T, nullptr, P12b, N_NODES, CDIM, 1536, 1);
    hipMemsetAsync(agg, 0, (size_t)N_NODES * HCDIM * sizeof(float), stream);
    edge_kernel<<<dim3(N_EDGES / 16), dim3(256), 0, stream>>>(
        qbb, kbb, efb, ei, WcT, P12b, cbv,
        ln_a_g + i * C3DIM, ln_a_b + i * C3DIM,
        WmTb, bm + i * CDIM,
        ln_m_g + i * CDIM, ln_m_b + i * CDIM, agg, N_EDGES);
    pack_bf16_kernel<<<dim3((N_NODES * 256 + 255) / 256), dim3(256), 0, stream>>>(agg, aggb, N_NODES * 256);
    mgemm(aggb, WcTw, bc + i * CDIM, o, N_NODES, HCDIM, CDIM, 0);
    bn_stats_kernel<<<dim3(CDIM), dim3(256), 0, stream>>>(o, mu, rstd);
    mgemm(nfb, WskT, bskip + i * CDIM, skip, N_NODES, CDIM, CDIM, 0);
    bn_silu_skip_kernel<<<dim3((N_NODES * CDIM + 255) / 256), dim3(256), 0, stream>>>(
        o, skip, mu, rstd, bn_g + i * CDIM, bn_b + i * CDIM, nf);
  }

  hipMemsetAsync(psum, 0, (size_t)(N_GRAPH * CDIM + N_GRAPH) * sizeof(float), stream);
  pool_kernel<<<dim3((N_NODES * CDIM + 255) / 256), dim3(256), 0, stream>>>(nf, batch, psum, cnt);
  feats_kernel<<<dim3((N_GRAPH * 167 + 255) / 256), dim3(256), 0, stream>>>(psum, cnt, pge, cse, feats);
  gemm(feats, fc_W, fc_b, h, N_GRAPH, 167, 512, 1);
  out_kernel<<<dim3(N_GRAPH), dim3(256), 0, stream>>>(h, out_W, out_b, (float*)d_out);
}

// Round 6
// 1360.280 us; speedup vs baseline: 1.3248x; 1.0974x over previous
//
#include <hip/hip_runtime.h>
#include <math.h>

#define N_NODES 10000
#define N_EDGES 100000
#define N_GRAPH 64
#define CDIM 128
#define HCDIM 256
#define C3DIM 384

typedef unsigned short u16;
typedef __attribute__((ext_vector_type(8))) short bf16x8;
typedef __attribute__((ext_vector_type(4))) float f32x4;

__device__ __forceinline__ u16 f2bf(float f) {
  union { float f; unsigned int u; } x; x.f = f;
  unsigned int u = x.u + 0x7fffu + ((x.u >> 16) & 1u);
  return (u16)(u >> 16);
}
__device__ __forceinline__ float bf2f(u16 h) {
  union { unsigned int u; float f; } x; x.u = ((unsigned int)h) << 16;
  return x.f;
}

// ---------------- generic fp32 GEMM (odd-K cases); optional bf16 mirror ------
template<int ACT>
__global__ __launch_bounds__(256) void gemm_kernel(
    const float* __restrict__ A, const float* __restrict__ W,
    const float* __restrict__ bias, float* __restrict__ Y,
    u16* __restrict__ Yb, int M, int K, int N) {
  __shared__ float As[16][68];
  __shared__ float Bs[16][65];
  const int tid = threadIdx.x;
  const int bm = blockIdx.y * 64, bn = blockIdx.x * 64;
  const int tx = tid & 15, ty = tid >> 4;
  float acc[4][4] = {};
  for (int k0 = 0; k0 < K; k0 += 16) {
#pragma unroll
    for (int i = 0; i < 4; ++i) {
      int l = tid + i * 256;
      int kk = l & 15, m = l >> 4;
      int gm = bm + m, gk = k0 + kk;
      As[kk][m] = (gm < M && gk < K) ? A[(size_t)gm * K + gk] : 0.f;
    }
#pragma unroll
    for (int i = 0; i < 4; ++i) {
      int l = tid + i * 256;
      int n = l & 63, kk = l >> 6;
      int gk = k0 + kk, gn = bn + n;
      Bs[kk][n] = (gk < K && gn < N) ? W[(size_t)gk * N + gn] : 0.f;
    }
    __syncthreads();
#pragma unroll
    for (int kk = 0; kk < 16; ++kk) {
      float a[4], b[4];
#pragma unroll
      for (int i = 0; i < 4; ++i) a[i] = As[kk][ty * 4 + i];
#pragma unroll
      for (int j = 0; j < 4; ++j) b[j] = Bs[kk][tx * 4 + j];
#pragma unroll
      for (int i = 0; i < 4; ++i)
#pragma unroll
        for (int j = 0; j < 4; ++j) acc[i][j] += a[i] * b[j];
    }
    __syncthreads();
  }
#pragma unroll
  for (int i = 0; i < 4; ++i) {
    int gm = bm + ty * 4 + i;
    if (gm >= M) continue;
#pragma unroll
    for (int j = 0; j < 4; ++j) {
      int gn = bn + tx * 4 + j;
      if (gn >= N) continue;
      float val = acc[i][j] + (bias ? bias[gn] : 0.f);
      if (ACT == 1) val = val / (1.f + expf(-val));
      if (Y)  Y[(size_t)gm * N + gn] = val;
      if (Yb) Yb[(size_t)gm * N + gn] = f2bf(val);
    }
  }
}

// ---------------- MFMA dense GEMM: Y[M,N] = Ab[M,K] @ WT[N,K]^T (+bias) ------
template<int OUT_BF16>
__global__ __launch_bounds__(256) void mfma_gemm_kernel(
    const u16* __restrict__ Ab, const u16* __restrict__ WT,
    const float* __restrict__ bias, void* __restrict__ Y,
    int M, int K, int N) {
  const int tid = threadIdx.x;
  const int w = tid >> 6, l = tid & 63;
  const int lq = l >> 4, ln = l & 15;
  const int bm = blockIdx.y * 128, bn = blockIdx.x * 64;
  int ra = bm + w * 32 + ln;      if (ra > M - 1) ra = M - 1;
  int rb = bm + w * 32 + 16 + ln; if (rb > M - 1) rb = M - 1;
  f32x4 acc[2][4];
#pragma unroll
  for (int g = 0; g < 2; ++g)
#pragma unroll
    for (int nt = 0; nt < 4; ++nt) acc[g][nt] = {0.f, 0.f, 0.f, 0.f};
  for (int k0 = 0; k0 < K; k0 += 32) {
    bf16x8 a0 = *(const bf16x8*)&Ab[(size_t)ra * K + k0 + lq * 8];
    bf16x8 a1 = *(const bf16x8*)&Ab[(size_t)rb * K + k0 + lq * 8];
#pragma unroll
    for (int nt = 0; nt < 4; ++nt) {
      bf16x8 b = *(const bf16x8*)&WT[(size_t)(bn + nt * 16 + ln) * K + k0 + lq * 8];
      acc[0][nt] = __builtin_amdgcn_mfma_f32_16x16x32_bf16(a0, b, acc[0][nt], 0, 0, 0);
      acc[1][nt] = __builtin_amdgcn_mfma_f32_16x16x32_bf16(a1, b, acc[1][nt], 0, 0, 0);
    }
  }
#pragma unroll
  for (int g = 0; g < 2; ++g) {
    int rowbase = bm + w * 32 + g * 16 + lq * 4;
#pragma unroll
    for (int nt = 0; nt < 4; ++nt) {
      int gn = bn + nt * 16 + ln;
      float bv = bias ? bias[gn] : 0.f;
#pragma unroll
      for (int r = 0; r < 4; ++r) {
        int gm = rowbase + r;
        if (gm < M) {
          float val = acc[g][nt][r] + bv;
          if (OUT_BF16) ((u16*)Y)[(size_t)gm * N + gn] = f2bf(val);
          else          ((float*)Y)[(size_t)gm * N + gn] = val;
        }
      }
    }
  }
}

// ---------------- weight composition (fp32) ----------------------------------
__global__ __launch_bounds__(256) void compose_kernel(
    const float* __restrict__ Wv, const float* __restrict__ We,
    const float* __restrict__ Wmu, float* __restrict__ WP12,
    float* __restrict__ WPe) {
  const int z = blockIdx.z;
  const float* Ap; const float* Bp; float* Cp; int ldc;
  if (z < 4) {
    int part = z >> 1, h = z & 1;
    Ap = Wv + h * 128; Bp = Wmu + part * 128 * 384;
    Cp = WP12 + part * 768 + h * 384; ldc = 1536;
  } else {
    int h = z - 4;
    Ap = We + h * 128; Bp = Wmu + 256 * 384;
    Cp = WPe + h * 384; ldc = 768;
  }
  __shared__ float As[16][68];
  __shared__ float Bs[16][65];
  const int tid = threadIdx.x;
  const int bm = blockIdx.y * 64, bn = blockIdx.x * 64;
  const int tx = tid & 15, ty = tid >> 4;
  float acc[4][4] = {};
  for (int k0 = 0; k0 < 128; k0 += 16) {
#pragma unroll
    for (int i = 0; i < 4; ++i) {
      int l = tid + i * 256;
      int kk = l & 15, m = l >> 4;
      As[kk][m] = Ap[(size_t)(bm + m) * 256 + k0 + kk];
    }
#pragma unroll
    for (int i = 0; i < 4; ++i) {
      int l = tid + i * 256;
      int n = l & 63, kk = l >> 6;
      Bs[kk][n] = Bp[(size_t)(k0 + kk) * 384 + bn + n];
    }
    __syncthreads();
#pragma unroll
    for (int kk = 0; kk < 16; ++kk) {
      float a[4], b[4];
#pragma unroll
      for (int i = 0; i < 4; ++i) a[i] = As[kk][ty * 4 + i];
#pragma unroll
      for (int j = 0; j < 4; ++j) b[j] = Bs[kk][tx * 4 + j];
#pragma unroll
      for (int i = 0; i < 4; ++i)
#pragma unroll
        for (int j = 0; j < 4; ++j) acc[i][j] += a[i] * b[j];
    }
    __syncthreads();
  }
#pragma unroll
  for (int i = 0; i < 4; ++i)
#pragma unroll
    for (int j = 0; j < 4; ++j)
      Cp[(size_t)(bm + ty * 4 + i) * ldc + bn + tx * 4 + j] = acc[i][j];
}

// ---------------- merged pack kernels (z-sliced) -----------------------------
// z0: Wq->WallT[0:256]  z1: Wk->WallT[256:512]  z2: WcTw  z3: WskT  z4: WmTb
// z5: cbv  z6: ball (bias for [q|k|P12] mega-GEMM)
__global__ void pack_all_kernel(
    const float* __restrict__ Wq, const float* __restrict__ Wk,
    const float* __restrict__ Wc, const float* __restrict__ Wsk,
    const float* __restrict__ Wm_l, const float* __restrict__ bmu,
    const float* __restrict__ bv_l, const float* __restrict__ Wmu,
    const float* __restrict__ bq_l, const float* __restrict__ bk_l,
    u16* __restrict__ WallT, u16* __restrict__ WcTw, u16* __restrict__ WskT,
    u16* __restrict__ WmTb, float* __restrict__ cbv, float* __restrict__ ball) {
  int z = blockIdx.y;
  int idx = blockIdx.x * 256 + threadIdx.x;
  if (z == 0) {
    if (idx < 32768) { int col = idx >> 7, kk = idx & 127;
      WallT[(size_t)col * 128 + kk] = f2bf(Wq[(size_t)kk * 256 + col]); }
  } else if (z == 1) {
    if (idx < 32768) { int col = idx >> 7, kk = idx & 127;
      WallT[(size_t)(256 + col) * 128 + kk] = f2bf(Wk[(size_t)kk * 256 + col]); }
  } else if (z == 2) {
    if (idx < 32768) { int col = idx >> 8, kk = idx & 255;
      WcTw[(size_t)col * 256 + kk] = f2bf(Wc[(size_t)kk * 128 + col]); }
  } else if (z == 3) {
    if (idx < 16384) { int col = idx >> 7, kk = idx & 127;
      WskT[(size_t)col * 128 + kk] = f2bf(Wsk[(size_t)kk * 128 + col]); }
  } else if (z == 4) {
    if (idx < 49152) { int col = idx / 384, kk = idx - col * 384;
      WmTb[idx] = f2bf(Wm_l[(size_t)kk * 128 + col]); }
  } else if (z == 5) {
    if (idx < 768) {
      int h2 = idx / 384, g = idx - h2 * 384;
      float s = bmu[g];
      for (int d = 0; d < 128; ++d)
        s += bv_l[h2 * 128 + d] * (Wmu[(size_t)d * 384 + g] + Wmu[(size_t)(128 + d) * 384 + g]);
      cbv[idx] = s;
    }
  } else {
    if (idx < 2048) {
      float v = 0.f;
      if (idx < 256) v = bq_l[idx];
      else if (idx < 512) v = bk_l[idx - 256];
      ball[idx] = v;
    }
  }
}

// z0: [We|WPe] -> WcT   z1: WP12 -> WallT[512:2048]
__global__ void packcomb_kernel(const float* __restrict__ We_l,
                                const float* __restrict__ WPe,
                                const float* __restrict__ WP12,
                                u16* __restrict__ WcT, u16* __restrict__ WallT) {
  int z = blockIdx.y;
  int idx = blockIdx.x * 256 + threadIdx.x;
  if (z == 0) {
    if (idx < 131072) { int col = idx >> 7, kk = idx & 127;
      float v = (col < 256) ? We_l[(size_t)kk * 256 + col]
                            : WPe[(size_t)kk * 768 + (col - 256)];
      WcT[idx] = f2bf(v); }
  } else {
    if (idx < 196608) { int col = idx >> 7, kk = idx & 127;
      WallT[(size_t)(512 + col) * 128 + kk] = f2bf(WP12[(size_t)kk * 1536 + col]); }
  }
}

__global__ void pack_bf16_kernel(const float* __restrict__ A, u16* __restrict__ B, int n) {
  int idx = blockIdx.x * blockDim.x + threadIdx.x;
  if (idx < n) B[idx] = f2bf(A[idx]);
}

// ---------------- fused per-edge kernel (MFMA, 16 edges/block) ---------------
// qkp row layout per node: [q(256) | k(256) | P12(1536)]  (2048 bf16)
// Phase A and Phase 4 share one (row=r, lane=lx) mapping -> gate stays in
// registers; no gate LDS buffer; LDS 45.4 KB -> 3 blocks/CU.
__global__ __launch_bounds__(256, 3) void edge_kernel(
    const u16* __restrict__ qkp, const u16* __restrict__ efb,
    const int* __restrict__ ei, const u16* __restrict__ WcT,
    const float* __restrict__ cbv,
    const float* __restrict__ lag, const float* __restrict__ lab,
    const u16* __restrict__ WmT, const float* __restrict__ bm_l,
    const float* __restrict__ lmg, const float* __restrict__ lmb,
    float* __restrict__ agg, int E) {
  __shared__ __align__(16) u16 C1[16 * 1032];
  __shared__ __align__(16) u16 A2p[12 * 512];   // aliased as C2 float[16][132]
  __shared__ int did16[16];
  float* C2 = (float*)A2p;
  const int tid = threadIdx.x;
  const int e0 = blockIdx.x * 16;
  const int w = tid >> 6, l = tid & 63;
  const int lq = l >> 4, ln = l & 15;
  const float scale = 0.051031036307982884f;  // 1/sqrt(384)

  if (tid < 16) did16[tid] = ei[E + e0 + tid];

  // thread mapping for Phase A+4: row r = hA*8+eA, 16 lanes lx per row
  const int r = tid >> 4, lx = tid & 15;
  const int hA = r >> 3, eA = r & 7;

  // ---- Prefetch gathers for both sub-batches ----
  bf16x8 qv[2], kdv[2], ksv[2], pdv[2][3], psv[2][3];
#pragma unroll
  for (int s = 0; s < 2; ++s) {
    int edge = e0 + s * 8 + eA;
    int dstn = ei[E + edge], srcn = ei[edge];
    const u16* db = qkp + (size_t)dstn * 2048;
    const u16* sb = qkp + (size_t)srcn * 2048;
    qv[s]  = *(const bf16x8*)&db[hA * 128 + lx * 8];
    kdv[s] = *(const bf16x8*)&db[256 + hA * 128 + lx * 8];
    ksv[s] = *(const bf16x8*)&sb[256 + hA * 128 + lx * 8];
#pragma unroll
    for (int p = 0; p < 3; ++p) {
      pdv[s][p] = *(const bf16x8*)&db[512 + hA * 384 + p * 128 + lx * 8];
      psv[s][p] = *(const bf16x8*)&sb[512 + 768 + hA * 384 + p * 128 + lx * 8];
    }
  }

  // ---- GEMM1: C1[16][1024] = efb @ WcT ----
  {
    bf16x8 afr[4];
    const u16* ab = efb + (size_t)(e0 + ln) * 128 + lq * 8;
#pragma unroll
    for (int ks = 0; ks < 4; ++ks) afr[ks] = *(const bf16x8*)(ab + ks * 32);
    for (int nt = 0; nt < 16; ++nt) {
      int g = w * 16 + nt;
      const u16* bb = WcT + (size_t)(g * 16 + ln) * 128 + lq * 8;
      f32x4 acc = {0.f, 0.f, 0.f, 0.f};
#pragma unroll
      for (int ks = 0; ks < 4; ++ks)
        acc = __builtin_amdgcn_mfma_f32_16x16x32_bf16(
            afr[ks], *(const bf16x8*)(bb + ks * 32), acc, 0, 0, 0);
      int col = g * 16 + ln;
#pragma unroll
      for (int rr = 0; rr < 4; ++rr) C1[(lq * 4 + rr) * 1032 + col] = f2bf(acc[rr]);
    }
  }
  __syncthreads();

  for (int s = 0; s < 2; ++s) {
    // ---- Phase A+4 fused: alpha -> LN384 -> gate (regs) -> t -> A2p ----
    {
      bf16x8 sea = *(const bf16x8*)&C1[(s * 8 + eA) * 1032 + hA * 128 + lx * 8];
      float a0[8], a1[8], a2[8];
      float sacc = 0.f, s2acc = 0.f;
#pragma unroll
      for (int j = 0; j < 8; ++j) {
        float qf = bf2f((u16)qv[s][j]);
        float x0 = qf * bf2f((u16)kdv[s][j]) * scale;
        float x1 = qf * bf2f((u16)ksv[s][j]) * scale;
        float x2 = qf * bf2f((u16)sea[j]) * scale;
        a0[j] = x0; a1[j] = x1; a2[j] = x2;
        sacc += x0 + x1 + x2;
        s2acc += x0 * x0 + x1 * x1 + x2 * x2;
      }
#pragma unroll
      for (int mm = 1; mm < 16; mm <<= 1) {
        sacc += __shfl_xor(sacc, mm); s2acc += __shfl_xor(s2acc, mm);
      }
      float mean = sacc * (1.f / C3DIM);
      float rstd = rsqrtf(s2acc * (1.f / C3DIM) - mean * mean + 1e-5f);
#pragma unroll
      for (int p = 0; p < 3; ++p) {
        const float* lg = lag + p * 128 + lx * 8;
        const float* lb = lab + p * 128 + lx * 8;
        f32x4 g0 = *(const f32x4*)lg, g1 = *(const f32x4*)(lg + 4);
        f32x4 b0 = *(const f32x4*)lb, b1 = *(const f32x4*)(lb + 4);
        f32x4 c0 = *(const f32x4*)&cbv[hA * 384 + p * 128 + lx * 8];
        f32x4 c1 = *(const f32x4*)&cbv[hA * 384 + p * 128 + lx * 8 + 4];
        bf16x8 pe = *(const bf16x8*)&C1[(s * 8 + eA) * 1032 + 256 + hA * 384 + p * 128 + lx * 8];
        bf16x8 outv;
#pragma unroll
        for (int j = 0; j < 8; ++j) {
          float av = p == 0 ? a0[j] : (p == 1 ? a1[j] : a2[j]);
          float gg = j < 4 ? g0[j] : g1[j - 4];
          float bb2 = j < 4 ? b0[j] : b1[j - 4];
          float cbj = j < 4 ? c0[j] : c1[j - 4];
          float z = (av - mean) * rstd * gg + bb2;
          float gate = 1.f / (1.f + expf(-z));
          float t = (bf2f((u16)pe[j]) + bf2f((u16)pdv[s][p][j]) +
                     bf2f((u16)psv[s][p][j]) + cbj) * gate;
          outv[j] = (short)f2bf(t);
        }
        int ks = p * 4 + (lx >> 2), qq = lx & 3;
        int slot = (((r ^ (qq << 2)) + ks) & 15) | (qq << 4);
        *(bf16x8*)&A2p[ks * 512 + slot * 8] = outv;
      }
    }
    __syncthreads();

    // ---- GEMM2: load A2 frags (swizzled), barrier, MFMA, write C2 (aliased) -
    {
      bf16x8 af2[12];
#pragma unroll
      for (int ks = 0; ks < 12; ++ks) {
        int slot = (((ln ^ (lq << 2)) + ks) & 15) | (lq << 4);
        af2[ks] = *(const bf16x8*)&A2p[ks * 512 + slot * 8];
      }
      __syncthreads();  // all reads of A2p complete before aliased C2 writes
#pragma unroll
      for (int nt = 0; nt < 2; ++nt) {
        int g = w * 2 + nt;
        const u16* bb = WmT + (size_t)(g * 16 + ln) * 384 + lq * 8;
        f32x4 acc = {0.f, 0.f, 0.f, 0.f};
#pragma unroll
        for (int ks = 0; ks < 12; ++ks)
          acc = __builtin_amdgcn_mfma_f32_16x16x32_bf16(
              af2[ks], *(const bf16x8*)(bb + ks * 32), acc, 0, 0, 0);
        int col = g * 16 + ln;
        float bcol = bm_l[col];
#pragma unroll
        for (int rr = 0; rr < 4; ++rr) C2[(lq * 4 + rr) * 132 + col] = acc[rr] + bcol;
      }
    }
    __syncthreads();

    // ---- LN128 + scatter ----
    {
      for (int rw = w; rw < 16; rw += 4) {
        float v0 = C2[rw * 132 + l], v1 = C2[rw * 132 + l + 64];
        float sa = v0 + v1, s2a = v0 * v0 + v1 * v1;
#pragma unroll
        for (int off2 = 32; off2 > 0; off2 >>= 1) {
          sa += __shfl_down(sa, off2); s2a += __shfl_down(s2a, off2);
        }
        sa = __shfl(sa, 0); s2a = __shfl(s2a, 0);
        float mean = sa * (1.f / CDIM);
        float rstd = rsqrtf(s2a * (1.f / CDIM) - mean * mean + 1e-5f);
        int h = rw >> 3, e = rw & 7;
        int dstn = did16[s * 8 + e];
        float o0 = (v0 - mean) * rstd * lmg[l] + lmb[l];
        float o1 = (v1 - mean) * rstd * lmg[l + 64] + lmb[l + 64];
        atomicAdd(&agg[(size_t)dstn * HCDIM + h * CDIM + l], o0);
        atomicAdd(&agg[(size_t)dstn * HCDIM + h * CDIM + l + 64], o1);
      }
    }
    __syncthreads();
  }
}

// ---------------- BN statistics ---------------------------------------------
__global__ __launch_bounds__(256) void bn_stats_kernel(
    const float* __restrict__ o, float* __restrict__ mu, float* __restrict__ rstd) {
  int c = blockIdx.x, tid = threadIdx.x;
  float s = 0.f, s2 = 0.f;
  for (int r = tid; r < N_NODES; r += 256) {
    float x = o[(size_t)r * CDIM + c];
    s += x; s2 += x * x;
  }
  __shared__ float red[8];
#pragma unroll
  for (int off = 32; off > 0; off >>= 1) {
    s += __shfl_down(s, off); s2 += __shfl_down(s2, off);
  }
  if ((tid & 63) == 0) { red[tid >> 6] = s; red[4 + (tid >> 6)] = s2; }
  __syncthreads();
  if (tid == 0) {
    float ts = red[0] + red[1] + red[2] + red[3];
    float t2 = red[4] + red[5] + red[6] + red[7];
    float m = ts * (1.f / N_NODES);
    float var = t2 * (1.f / N_NODES) - m * m;
    mu[c] = m;
    rstd[c] = rsqrtf(var + 1e-5f);
  }
}

// BN + SiLU + skip; also writes bf16 mirror of nf for next layer's GEMMs
__global__ void bn_silu_skip_kernel(
    const float* __restrict__ o, const float* __restrict__ skip,
    const float* __restrict__ mu, const float* __restrict__ rstd,
    const float* __restrict__ g, const float* __restrict__ b,
    float* __restrict__ nf, u16* __restrict__ nfb) {
  int idx = blockIdx.x * blockDim.x + threadIdx.x;
  if (idx >= N_NODES * CDIM) return;
  int c = idx & (CDIM - 1);
  float x = (o[idx] - mu[c]) * rstd[c] * g[c] + b[c];
  float sig = 1.f / (1.f + expf(-x));
  float val = x * sig + skip[idx];
  nf[idx] = val;
  nfb[idx] = f2bf(val);
}

__global__ void pool_kernel(const float* __restrict__ nf, const int* __restrict__ batch,
                            float* __restrict__ psum, float* __restrict__ cnt) {
  int idx = blockIdx.x * blockDim.x + threadIdx.x;
  if (idx >= N_NODES * CDIM) return;
  int n = idx >> 7, c = idx & 127;
  int b = batch[n];
  atomicAdd(&psum[b * CDIM + c], nf[idx]);
  if (c == 0) atomicAdd(&cnt[b], 1.f);
}

__global__ void feats_kernel(const float* __restrict__ psum, const float* __restrict__ cnt,
                             const float* __restrict__ pge, const float* __restrict__ cse,
                             float* __restrict__ feats) {
  int idx = blockIdx.x * blockDim.x + threadIdx.x;
  if (idx >= N_GRAPH * 167) return;
  int b = idx / 167, j = idx - b * 167;
  float val;
  if (j < 128)      val = psum[b * CDIM + j] / fmaxf(cnt[b], 1.f);
  else if (j < 160) val = pge[b * 32 + (j - 128)];
  else              val = cse[b * 7 + (j - 160)];
  feats[idx] = val;
}

__global__ __launch_bounds__(256) void out_kernel(
    const float* __restrict__ h, const float* __restrict__ ow,
    const float* __restrict__ ob, float* __restrict__ out) {
  int b = blockIdx.x, tid = threadIdx.x;
  float s = h[b * 512 + tid] * ow[tid] + h[b * 512 + tid + 256] * ow[tid + 256];
  __shared__ float red[4];
#pragma unroll
  for (int off = 32; off > 0; off >>= 1) s += __shfl_down(s, off);
  if ((tid & 63) == 0) red[tid >> 6] = s;
  __syncthreads();
  if (tid == 0) out[b] = red[0] + red[1] + red[2] + red[3] + ob[0];
}

// ---------------- launch -----------------------------------------------------
extern "C" void kernel_launch(void* const* d_in, const int* in_sizes, int n_in,
                              void* d_out, int out_size, void* d_ws, size_t ws_size,
                              hipStream_t stream) {
  const float* x         = (const float*)d_in[0];
  const float* edge_attr = (const float*)d_in[1];
  const float* pge       = (const float*)d_in[2];
  const float* cse       = (const float*)d_in[3];
  const int*   ei        = (const int*)d_in[4];
  const int*   batch     = (const int*)d_in[5];
  const float* atom_W    = (const float*)d_in[6];
  const float* atom_b    = (const float*)d_in[7];
  const float* edge_W    = (const float*)d_in[8];
  const float* edge_b    = (const float*)d_in[9];
  const float* Wq        = (const float*)d_in[10];
  const float* bq        = (const float*)d_in[11];
  const float* Wk        = (const float*)d_in[12];
  const float* bk        = (const float*)d_in[13];
  const float* Wv        = (const float*)d_in[14];
  const float* bv        = (const float*)d_in[15];
  const float* We        = (const float*)d_in[16];
  const float* Wmu       = (const float*)d_in[17];
  const float* bmu       = (const float*)d_in[18];
  const float* Wm        = (const float*)d_in[19];
  const float* bm        = (const float*)d_in[20];
  const float* ln_m_g    = (const float*)d_in[21];
  const float* ln_m_b    = (const float*)d_in[22];
  const float* ln_a_g    = (const float*)d_in[23];
  const float* ln_a_b    = (const float*)d_in[24];
  const float* Wc        = (const float*)d_in[25];
  const float* bc        = (const float*)d_in[26];
  const float* bn_g      = (const float*)d_in[27];
  const float* bn_b      = (const float*)d_in[28];
  const float* Wskip     = (const float*)d_in[29];
  const float* bskip     = (const float*)d_in[30];
  const float* fc_W      = (const float*)d_in[31];
  const float* fc_b      = (const float*)d_in[32];
  const float* out_W     = (const float*)d_in[33];
  const float* out_b     = (const float*)d_in[34];

  float* ws = (float*)d_ws;
  size_t off = 0;
  float* nf    = ws + off; off += (size_t)N_NODES * CDIM;
  float* agg   = ws + off; off += (size_t)N_NODES * HCDIM;
  float* o     = ws + off; off += (size_t)N_NODES * CDIM;
  float* skip  = ws + off; off += (size_t)N_NODES * CDIM;
  float* WP12  = ws + off; off += (size_t)128 * 1536;
  float* WPe   = ws + off; off += (size_t)128 * 768;
  float* cbv   = ws + off; off += 768;
  float* ball  = ws + off; off += 2048;
  float* mu    = ws + off; off += CDIM;
  float* rstd  = ws + off; off += CDIM;
  float* psum  = ws + off; off += (size_t)N_GRAPH * CDIM;
  float* cnt   = ws + off; off += N_GRAPH;
  float* feats = ws + off; off += (size_t)N_GRAPH * 167;
  float* h     = ws + off; off += (size_t)N_GRAPH * 512;
  u16* efb   = (u16*)(ws + off); off += (size_t)N_EDGES * 64;     // E*128 u16
  u16* WcT   = (u16*)(ws + off); off += 65536;                    // 1024*128 u16
  u16* WmTb  = (u16*)(ws + off); off += 24576;                    // 128*384 u16
  u16* nfb   = (u16*)(ws + off); off += (size_t)N_NODES * 64;     // N*128 u16
  u16* aggb  = (u16*)(ws + off); off += (size_t)N_NODES * 128;    // N*256 u16
  u16* qkp   = (u16*)(ws + off); off += (size_t)N_NODES * 1024;   // N*2048 u16
  u16* WallT = (u16*)(ws + off); off += 131072;                   // 2048*128 u16
  u16* WcTw  = (u16*)(ws + off); off += 16384;                    // 128*256 u16
  u16* WskT  = (u16*)(ws + off); off += 8192;                     // 128*128 u16

  auto mgemm = [&](const u16* Ab, const u16* WT, const float* bias, void* Y,
                   int M, int K, int Nn, int out_bf16) {
    dim3 grid(Nn / 64, (M + 127) / 128);
    if (out_bf16) mfma_gemm_kernel<1><<<grid, 256, 0, stream>>>(Ab, WT, bias, Y, M, K, Nn);
    else          mfma_gemm_kernel<0><<<grid, 256, 0, stream>>>(Ab, WT, bias, Y, M, K, Nn);
  };

  // nf = x@atom_W (+bf16 mirror), efb = bf16(edge_attr@edge_W)
  gemm_kernel<0><<<dim3(2, 157), 256, 0, stream>>>(x, atom_W, atom_b, nf, nfb,
                                                   N_NODES, 92, CDIM);
  gemm_kernel<0><<<dim3(2, 1563), 256, 0, stream>>>(edge_attr, edge_W, edge_b,
                                                    nullptr, efb, N_EDGES, 50, CDIM);

  for (int i = 0; i < 2; ++i) {
    const float* Wv_i  = Wv + (size_t)i * CDIM * HCDIM;
    const float* We_i  = We + (size_t)i * CDIM * HCDIM;
    const float* Wmu_i = Wmu + (size_t)i * C3DIM * C3DIM;
    compose_kernel<<<dim3(6, 2, 6), 256, 0, stream>>>(Wv_i, We_i, Wmu_i, WP12, WPe);
    pack_all_kernel<<<dim3(192, 7), 256, 0, stream>>>(
        Wq + (size_t)i * CDIM * HCDIM, Wk + (size_t)i * CDIM * HCDIM,
        Wc + (size_t)i * HCDIM * CDIM, Wskip + (size_t)i * CDIM * CDIM,
        Wm + (size_t)i * C3DIM * CDIM, bmu + i * C3DIM, bv + i * HCDIM, Wmu_i,
        bq + i * HCDIM, bk + i * HCDIM,
        WallT, WcTw, WskT, WmTb, cbv, ball);
    packcomb_kernel<<<dim3(768, 2), 256, 0, stream>>>(We_i, WPe, WP12, WcT, WallT);

    // qkp = nfb @ [Wq|Wk|WP12]  (N=2048, bf16 out)
    mgemm(nfb, WallT, ball, qkp, N_NODES, CDIM, 2048, 1);

    hipMemsetAsync(agg, 0, (size_t)N_NODES * HCDIM * sizeof(float), stream);
    edge_kernel<<<dim3(N_EDGES / 16), dim3(256), 0, stream>>>(
        qkp, efb, ei, WcT, cbv,
        ln_a_g + i * C3DIM, ln_a_b + i * C3DIM,
        WmTb, bm + i * CDIM,
        ln_m_g + i * CDIM, ln_m_b + i * CDIM, agg, N_EDGES);

    pack_bf16_kernel<<<dim3((N_NODES * 256 + 255) / 256), dim3(256), 0, stream>>>(
        agg, aggb, N_NODES * 256);
    mgemm(aggb, WcTw, bc + i * CDIM, o, N_NODES, HCDIM, CDIM, 0);
    bn_stats_kernel<<<dim3(CDIM), dim3(256), 0, stream>>>(o, mu, rstd);
    mgemm(nfb, WskT, bskip + i * CDIM, skip, N_NODES, CDIM, CDIM, 0);
    bn_silu_skip_kernel<<<dim3((N_NODES * CDIM + 255) / 256), dim3(256), 0, stream>>>(
        o, skip, mu, rstd, bn_g + i * CDIM, bn_b + i * CDIM, nf, nfb);
  }

  hipMemsetAsync(psum, 0, (size_t)(N_GRAPH * CDIM + N_GRAPH) * sizeof(float), stream);
  pool_kernel<<<dim3((N_NODES * CDIM + 255) / 256), dim3(256), 0, stream>>>(nf, batch, psum, cnt);
  feats_kernel<<<dim3((N_GRAPH * 167 + 255) / 256), dim3(256), 0, stream>>>(psum, cnt, pge, cse, feats);
  gemm_kernel<1><<<dim3(8, 1), 256, 0, stream>>>(feats, fc_W, fc_b, h, nullptr,
                                                 N_GRAPH, 167, 512);
  out_kernel<<<dim3(N_GRAPH), 256, 0, stream>>>(h, out_W, out_b, (float*)d_out);
}